// Round 7
// baseline (576.389 us; speedup 1.0000x reference)
//
#include <hip/hip_runtime.h>
#include <hip/hip_bf16.h>
#include <math.h>

#define BF16 __hip_bfloat16

typedef __bf16 bf16x8 __attribute__((ext_vector_type(8)));
typedef float  f32x4  __attribute__((ext_vector_type(4)));
typedef float  f32x16 __attribute__((ext_vector_type(16)));

// branch-free erf (Abramowitz-Stegun 7.1.26, |err| < 1.5e-7)
__device__ inline float gelu_erf(float x) {
  float xs = x * 0.70710678118654752f;
  float a = fabsf(xs);
  float t = __builtin_amdgcn_rcpf(1.0f + 0.3275911f * a);
  float p = 1.061405429f;
  p = p * t - 1.453152027f;
  p = p * t + 1.421413741f;
  p = p * t - 0.284496736f;
  p = p * t + 0.254829592f;
  float e = __expf(-a * a);
  float y = 1.0f - p * t * e;
  float s = copysignf(y, xs);
  return 0.5f * x * (1.0f + s);
}

__device__ inline void gload_lds16(const void* g, void* s) {
  __builtin_amdgcn_global_load_lds(
      (const __attribute__((address_space(1))) unsigned int*)g,
      (__attribute__((address_space(3))) unsigned int*)s, 16, 0, 0);
}

struct WPtrs { const float* p[9]; };
struct FArgs { const BF16* w[5]; const float* b[5]; };

// ---------------- small prep kernels ----------------
// Weights in kt-major fragment order:
//   elem index = kt*8192 + wc*2048 + nc*512 + (fq*16+fr)*8 + e
//   source     = W[wc*64+nc*16+fr][kt*32+fq*8+e]
// -> each kt-slice is 16 KB contiguous; chunk (wc,nc) is 1024 contiguous bytes.
__global__ void cast_w_kernel(WPtrs wp, BF16* __restrict__ out) {
  int i = blockIdx.x * 256 + threadIdx.x;   // < 9*65536
  int seg = i >> 16, d = i & 65535;
  int e = d & 7, lane = (d >> 3) & 63;
  int nc = (d >> 9) & 3, wc = (d >> 11) & 3, kt = (d >> 13) & 7;
  int fr = lane & 15, fq = lane >> 4;
  int row = wc * 64 + nc * 16 + fr, col = kt * 32 + fq * 8 + e;
  out[i] = __float2bfloat16(wp.p[seg][row * 256 + col]);
}

// W~[p, h*32+d] = sum_j mix_w[p, h*32+j] * latent_q[h*32+j, d], kt-major fragment order
__global__ void build_wtilde(const float* __restrict__ mixw, const float* __restrict__ lq,
                             BF16* __restrict__ wt) {
  int p = blockIdx.x, c = threadIdx.x;
  int h = c >> 5, d = c & 31;
  float s = 0.f;
#pragma unroll
  for (int j = 0; j < 32; ++j)
    s += mixw[p * 256 + h * 32 + j] * lq[(h * 32 + j) * 32 + d];
  int wc = p >> 6, nc = (p >> 4) & 3, fr = p & 15;
  int kt = c >> 5, fq = (c >> 3) & 3, e = c & 7;
  int dst = kt * 8192 + wc * 2048 + nc * 512 + (fq * 16 + fr) * 8 + e;
  wt[dst] = __float2bfloat16(s);
}

// ---------------- fused resident-tile MLP helpers ----------------
// stage one 16KB kt-slice of a layer's weights into LDS (all 4 waves cooperate)
__device__ inline void stageW(const BF16* Wl, int kt, char* buf, int wc, int lane) {
#pragma unroll
  for (int i = 0; i < 4; ++i) {
    int c = wc * 4 + i;        // chunk (wc,nc=i): wave-uniform LDS base
    gload_lds16((const char*)Wl + kt * 16384 + c * 1024 + lane * 16, buf + c * 1024);
  }
}

__device__ inline void loadb4(bf16x8 (&dst)[4], const char* buf, int wc, int lane) {
#pragma unroll
  for (int nc = 0; nc < 4; ++nc)
    dst[nc] = *(const bf16x8*)(buf + (wc * 4 + nc) * 1024 + lane * 16);
}

__device__ inline void loada4(bf16x8 (&dst)[4], const char* act, int kt, int fr, int fq) {
#pragma unroll
  for (int nr = 0; nr < 4; ++nr) {
    int r = nr * 16 + fr;
    dst[nr] = *(const bf16x8*)(act + r * 512 + ((kt * 64 + fq * 16) ^ ((r & 7) << 4)));
  }
}

__device__ inline void mfma16(f32x4 (&acc)[4][4], const bf16x8 (&bv)[4], const bf16x8 (&af)[4]) {
#pragma unroll
  for (int nr = 0; nr < 4; ++nr)
#pragma unroll
    for (int nc = 0; nc < 4; ++nc)
      acc[nr][nc] = __builtin_amdgcn_mfma_f32_16x16x32_bf16(bv[nc], af[nr], acc[nr][nc], 0, 0, 0);
}

// ---------------- fused resident-tile MLP ----------------
// VARIANT 0: k-MLP(4 layers) + mixed(=k@Wt^T, f32 out) + softmax-N partial stats
// VARIANT 1: v-MLP(4 layers) -> bf16 global
// VARIANT 2: final projection (1 layer, bias, f32 out)
// act tile: 64 rows x 256 cols bf16 (32KB), XOR-swizzled, resident across layers.
// weights: kt-major fragment order, staged via global_load_lds into a 2x16KB
// LDS double buffer (m97 mechanism: async DMA prefetch one phase ahead; the
// compiler's vmcnt(0)-before-barrier provides the 2-phase semantics; a second
// resident block hides the drain).
template <int VARIANT>
__global__ __launch_bounds__(256, 2) void fused_mlp(
    const float* __restrict__ xin, const BF16* __restrict__ oin, FArgs args,
    float* __restrict__ fout, BF16* __restrict__ bout,
    float* __restrict__ pm, float* __restrict__ ps) {
  __shared__ __align__(16) char act[64 * 512];
  __shared__ __align__(16) char wlds[2][16384];
  const int tid = threadIdx.x;
  const int blk = blockIdx.x;
  const int wc = tid >> 6, lane = tid & 63;
  const int fr = lane & 15, fq = lane >> 4;
  const size_t row0 = (size_t)blk * 64;

  // issue first weight-slice DMA before act staging so it overlaps
  stageW(args.w[0], 0, wlds[0], wc, lane);

  // ---- stage input tile into swizzled LDS ----
  if (VARIANT != 2) {
    const float* xg = xin + row0 * 256;
#pragma unroll
    for (int rep = 0; rep < 16; ++rep) {
      int i = rep * 256 + tid;               // float4 index in tile (4096 total)
      int r = i >> 6, c4 = (i & 63) << 2;
      float4 v = *(const float4*)(xg + r * 256 + c4);
      union { __bf16 h[4]; unsigned long long u; } p;
      p.h[0] = (__bf16)v.x; p.h[1] = (__bf16)v.y;
      p.h[2] = (__bf16)v.z; p.h[3] = (__bf16)v.w;
      int byte = r * 512 + ((c4 * 2) ^ ((r & 7) << 4));
      *(unsigned long long*)(act + byte) = p.u;
    }
  } else {
    const BF16* og = oin + row0 * 256;
#pragma unroll
    for (int rep = 0; rep < 8; ++rep) {
      int i = rep * 256 + tid;               // 16B granule index (2048 total)
      int r = i >> 5, g = i & 31;
      uint4 v = *(const uint4*)(og + r * 256 + g * 8);
      int byte = r * 512 + ((g * 16) ^ ((r & 7) << 4));
      *(uint4*)(act + byte) = v;
    }
  }
  __syncthreads();   // act ready + kt0 weights arrived (compiler drains vmcnt)

  const int NL = (VARIANT == 0) ? 5 : (VARIANT == 1 ? 4 : 1);
#pragma unroll 1
  for (int L = 0; L < NL; ++L) {
    const BF16* Wl = args.w[L];
    const BF16* Wn = (L + 1 < NL) ? args.w[L + 1] : args.w[L];
    f32x4 acc[4][4];
#pragma unroll
    for (int nr = 0; nr < 4; ++nr)
#pragma unroll
      for (int nc = 0; nc < 4; ++nc)
#pragma unroll
        for (int j = 0; j < 4; ++j) acc[nr][nc][j] = 0.f;

    // 2-phase K-loop: stage kt+1 (or next layer's kt0) while computing kt.
#pragma unroll
    for (int kt = 0; kt < 8; ++kt) {
      char* cur = wlds[kt & 1];
      char* nxt = wlds[(kt & 1) ^ 1];
      if (kt < 7) stageW(Wl, kt + 1, nxt, wc, lane);
      else        stageW(Wn, 0, nxt, wc, lane);
      bf16x8 af[4], bv[4];
      loada4(af, act, kt, fr, fq);
      loadb4(bv, cur, wc, lane);
      mfma16(acc, bv, af);
      __syncthreads();   // next stage arrived; cur free for restage; act reads done (kt7)
    }

    if (VARIANT == 0 && L == 4) {
      // mixed epilogue: f32 global + per-column (over 64 rows) max/sumexp partials
      float* mg = fout + row0 * 256;
#pragma unroll
      for (int nc = 0; nc < 4; ++nc) {
#pragma unroll
        for (int nr = 0; nr < 4; ++nr) {
          float4 st = { acc[nr][nc][0], acc[nr][nc][1], acc[nr][nc][2], acc[nr][nc][3] };
          *(float4*)(mg + (size_t)(nr * 16 + fr) * 256 + wc * 64 + nc * 16 + fq * 4) = st;
        }
        float mx[4], sm[4];
#pragma unroll
        for (int jj = 0; jj < 4; ++jj) {
          float m0 = fmaxf(fmaxf(acc[0][nc][jj], acc[1][nc][jj]),
                           fmaxf(acc[2][nc][jj], acc[3][nc][jj]));
#pragma unroll
          for (int d = 1; d < 16; d <<= 1) m0 = fmaxf(m0, __shfl_xor(m0, d));
          float s0 = 0.f;
#pragma unroll
          for (int nr = 0; nr < 4; ++nr) s0 += __expf(acc[nr][nc][jj] - m0);
#pragma unroll
          for (int d = 1; d < 16; d <<= 1) s0 += __shfl_xor(s0, d);
          mx[jj] = m0; sm[jj] = s0;
        }
        if (fr == 0) {
          int col = wc * 64 + nc * 16 + fq * 4;
          *(float4*)(pm + (size_t)blk * 256 + col) = {mx[0], mx[1], mx[2], mx[3]};
          *(float4*)(ps + (size_t)blk * 256 + col) = {sm[0], sm[1], sm[2], sm[3]};
        }
      }
    } else if (VARIANT == 2) {
      float* og = fout + row0 * 256;
#pragma unroll
      for (int nc = 0; nc < 4; ++nc) {
        float4 b4 = *(const float4*)(args.b[0] + wc * 64 + nc * 16 + fq * 4);
#pragma unroll
        for (int nr = 0; nr < 4; ++nr) {
          float4 st = { acc[nr][nc][0] + b4.x, acc[nr][nc][1] + b4.y,
                        acc[nr][nc][2] + b4.z, acc[nr][nc][3] + b4.w };
          *(float4*)(og + (size_t)(nr * 16 + fr) * 256 + wc * 64 + nc * 16 + fq * 4) = st;
        }
      }
    } else {
      // MLP layer epilogue: bias (+gelu for L<3) + residual; write LDS (or v to global)
      const float* bb = args.b[L];
#pragma unroll
      for (int nc = 0; nc < 4; ++nc) {
        float4 b4 = *(const float4*)(bb + wc * 64 + nc * 16 + fq * 4);
#pragma unroll
        for (int nr = 0; nr < 4; ++nr) {
          int r = nr * 16 + fr;
          int cb2 = wc * 128 + nc * 32 + fq * 8;     // byte offset of 4 bf16 cols
          int byte = r * 512 + (cb2 ^ ((r & 7) << 4));
          union { __bf16 h[4]; unsigned long long u; } res, w2;
          res.u = *(unsigned long long*)(act + byte);
          float o0 = acc[nr][nc][0] + b4.x;
          float o1 = acc[nr][nc][1] + b4.y;
          float o2 = acc[nr][nc][2] + b4.z;
          float o3 = acc[nr][nc][3] + b4.w;
          if (L < 3) { o0 = gelu_erf(o0); o1 = gelu_erf(o1);
                       o2 = gelu_erf(o2); o3 = gelu_erf(o3); }
          w2.h[0] = (__bf16)((float)res.h[0] + o0);
          w2.h[1] = (__bf16)((float)res.h[1] + o1);
          w2.h[2] = (__bf16)((float)res.h[2] + o2);
          w2.h[3] = (__bf16)((float)res.h[3] + o3);
          if (VARIANT == 1 && L == 3) {
            *(unsigned long long*)((char*)bout + ((row0 + r) * 512 + cb2)) = w2.u;
          } else {
            *(unsigned long long*)(act + byte) = w2.u;
          }
        }
      }
      if (L != NL - 1) __syncthreads();
    }
  }
}

// ---------------- softmax-over-N merge ----------------
__global__ void softmax_merge(const float* __restrict__ pm, const float* __restrict__ ps,
                              float* __restrict__ Mf, float* __restrict__ Sf) {
  int b = blockIdx.x, t = threadIdx.x;
  const float* pmb = pm + (size_t)b * 512 * 256;
  const float* psb = ps + (size_t)b * 512 * 256;
  float m = -3.0e38f, s = 0.f;
  for (int c = 0; c < 512; ++c) {
    float m2 = pmb[c * 256 + t];
    float s2 = psb[c * 256 + t];
    float mn = fmaxf(m, m2);
    s = s * __expf(m - mn) + s2 * __expf(m2 - mn);
    m = mn;
  }
  Mf[b * 256 + t] = m;
  Sf[b * 256 + t] = 1.f / s;
}

// ---------------- z = enc @ v (partials over n-chunks) ----------------
__global__ __launch_bounds__(256) void z_partial_mfma(
    const float* __restrict__ mixed, const BF16* __restrict__ v,
    const float* __restrict__ Mf, float* __restrict__ zpart) {
  int ci = blockIdx.x;                 // B*128 blocks, 256 rows each
  int b = ci >> 7, ch = ci & 127;
  int tid = threadIdx.x, wid = tid >> 6, lane = tid & 63;
  int l31 = lane & 31, kh = lane >> 5;
  size_t n0 = (size_t)b * 32768 + ch * 256;
  for (int hi = 0; hi < 2; ++hi) {
    int h = wid * 2 + hi;
    int col = h * 32 + l31;
    float Mp = Mf[b * 256 + col];
    f32x16 acc;
#pragma unroll
    for (int r = 0; r < 16; ++r) acc[r] = 0.f;
    for (int s = 0; s < 16; ++s) {
      bf16x8 ea, vb;
      size_t nbase = n0 + s * 16 + kh * 8;
#pragma unroll
      for (int j = 0; j < 8; ++j) {
        float x = __expf(mixed[(nbase + j) * 256 + col] - Mp);
        ea[j] = (__bf16)x;
        vb[j] = *(const __bf16*)&v[(nbase + j) * 256 + col];
      }
      acc = __builtin_amdgcn_mfma_f32_32x32x16_bf16(ea, vb, acc, 0, 0, 0);
    }
    float* zp = zpart + (size_t)ci * 8192 + h * 1024;
#pragma unroll
    for (int reg = 0; reg < 16; ++reg) {
      int m = (reg & 3) + 8 * (reg >> 2) + 4 * kh;
      zp[m * 32 + l31] = acc[reg];
    }
  }
}

__global__ void z_merge(const float* __restrict__ zpart, const float* __restrict__ Sf,
                        float* __restrict__ z) {
  int i = blockIdx.x * 256 + threadIdx.x;   // [0, 4*8192)
  int b = i >> 13, j = i & 8191;
  int p = j >> 5;                           // h*32 + m
  float s = 0.f;
  for (int c = 0; c < 128; ++c) s += zpart[(size_t)(b * 128 + c) * 8192 + j];
  z[i] = s * Sf[b * 256 + p];
}

// ---------------- o = dec^T @ z ----------------
__global__ __launch_bounds__(256) void decode_o_mfma(
    const float* __restrict__ mixed, const float* __restrict__ z,
    BF16* __restrict__ o) {
  int ci = blockIdx.x;                 // B*128 blocks, 256 rows each
  int b = ci >> 7, ch = ci & 127;
  int tid = threadIdx.x, wid = tid >> 6, lane = tid & 63;
  int l31 = lane & 31, kh = lane >> 5;
  size_t rowbase = (size_t)b * 32768 + ch * 256;
  for (int hi = 0; hi < 2; ++hi) {
    int h = wid * 2 + hi;
    bf16x8 zf[2];
#pragma unroll
    for (int ks = 0; ks < 2; ++ks)
#pragma unroll
      for (int j = 0; j < 8; ++j)
        zf[ks][j] = (__bf16)z[b * 8192 + h * 1024 + (ks * 16 + kh * 8 + j) * 32 + l31];
    for (int s = 0; s < 8; ++s) {
      size_t n = rowbase + s * 32 + l31;
      const float* mrow = mixed + n * 256 + h * 32;
      float xv[16];
#pragma unroll
      for (int ks = 0; ks < 2; ++ks) {
        float4 a  = *(const float4*)(mrow + ks * 16 + kh * 8);
        float4 c4 = *(const float4*)(mrow + ks * 16 + kh * 8 + 4);
        xv[ks * 8 + 0] = a.x;  xv[ks * 8 + 1] = a.y;  xv[ks * 8 + 2] = a.z;  xv[ks * 8 + 3] = a.w;
        xv[ks * 8 + 4] = c4.x; xv[ks * 8 + 5] = c4.y; xv[ks * 8 + 6] = c4.z; xv[ks * 8 + 7] = c4.w;
      }
      float mx = xv[0];
#pragma unroll
      for (int i = 1; i < 16; ++i) mx = fmaxf(mx, xv[i]);
      mx = fmaxf(mx, __shfl_xor(mx, 32));
      float sm = 0.f, ev[16];
#pragma unroll
      for (int i = 0; i < 16; ++i) { ev[i] = __expf(xv[i] - mx); sm += ev[i]; }
      sm += __shfl_xor(sm, 32);
      float inv = 1.f / sm;
      bf16x8 af[2];
#pragma unroll
      for (int ks = 0; ks < 2; ++ks)
#pragma unroll
        for (int j = 0; j < 8; ++j) af[ks][j] = (__bf16)(ev[ks * 8 + j] * inv);
      f32x16 acc;
#pragma unroll
      for (int r = 0; r < 16; ++r) acc[r] = 0.f;
      acc = __builtin_amdgcn_mfma_f32_32x32x16_bf16(af[0], zf[0], acc, 0, 0, 0);
      acc = __builtin_amdgcn_mfma_f32_32x32x16_bf16(af[1], zf[1], acc, 0, 0, 0);
#pragma unroll
      for (int reg = 0; reg < 16; ++reg) {
        int nr = (reg & 3) + 8 * (reg >> 2) + 4 * kh;
        o[(rowbase + s * 32 + nr) * 256 + h * 32 + l31] = __float2bfloat16(acc[reg]);
      }
    }
  }
}

// ---------------- launch ----------------
extern "C" void kernel_launch(void* const* d_in, const int* in_sizes, int n_in,
                              void* d_out, int out_size, void* d_ws, size_t ws_size,
                              hipStream_t stream) {
  const float* x     = (const float*)d_in[0];
  const float* lq    = (const float*)d_in[1];
  const float* kfc1b = (const float*)d_in[3];
  const float* kfcsb = (const float*)d_in[5];
  const float* kfc2b = (const float*)d_in[7];
  const float* vfc1b = (const float*)d_in[9];
  const float* vfcsb = (const float*)d_in[11];
  const float* vfc2b = (const float*)d_in[13];
  const float* mixw  = (const float*)d_in[14];
  const float* outb  = (const float*)d_in[16];

  const int R = in_sizes[0] / 256;          // 131072 rows (B*N)

  char* ws = (char*)d_ws;
  BF16*  v     = (BF16*)(ws);                    // 67,108,864 B
  BF16*  o     = (BF16*)(ws + 67108864);         // 67,108,864 B
  BF16*  wbf   = (BF16*)(ws + 134217728);        //  1,179,648 B
  BF16*  wt    = (BF16*)(ws + 135397376);        //    131,072 B
  float* pm    = (float*)(ws + 135528448);       //  2,097,152 B
  float* ps    = (float*)(ws + 137625600);       //  2,097,152 B
  float* Mf    = (float*)(ws + 139722752);       //      4,096 B
  float* Sf    = (float*)(ws + 139726848);       //      4,096 B
  float* zpart = (float*)(ws + 139730944);       // 16,777,216 B
  float* z     = (float*)(ws + 156508160);       //    131,072 B
  float* mixed = (float*)d_out;                  // d_out doubles as mixed (f32)

  // prep
  WPtrs wp = {{(const float*)d_in[2], (const float*)d_in[4], (const float*)d_in[4] + 65536,
               (const float*)d_in[6], (const float*)d_in[8], (const float*)d_in[10],
               (const float*)d_in[10] + 65536, (const float*)d_in[12], (const float*)d_in[15]}};
  cast_w_kernel<<<2304, 256, 0, stream>>>(wp, wbf);
  build_wtilde<<<256, 256, 0, stream>>>(mixw, lq, wt);

  const int G = R / 64;   // 2048

  // F1: k-MLP + mixed + stats
  FArgs a1;
  a1.w[0] = wbf + 0;      a1.b[0] = kfc1b;
  a1.w[1] = wbf + 65536;  a1.b[1] = kfcsb;
  a1.w[2] = wbf + 131072; a1.b[2] = kfcsb + 256;
  a1.w[3] = wbf + 196608; a1.b[3] = kfc2b;
  a1.w[4] = wt;           a1.b[4] = nullptr;
  fused_mlp<0><<<G, 256, 0, stream>>>(x, nullptr, a1, mixed, nullptr, pm, ps);

  // F2: v-MLP
  FArgs a2;
  a2.w[0] = wbf + 262144; a2.b[0] = vfc1b;
  a2.w[1] = wbf + 327680; a2.b[1] = vfcsb;
  a2.w[2] = wbf + 393216; a2.b[2] = vfcsb + 256;
  a2.w[3] = wbf + 458752; a2.b[3] = vfc2b;
  a2.w[4] = nullptr;      a2.b[4] = nullptr;
  fused_mlp<1><<<G, 256, 0, stream>>>(x, nullptr, a2, nullptr, v, nullptr, nullptr);

  // softmax-over-N merge
  softmax_merge<<<4, 256, 0, stream>>>(pm, ps, Mf, Sf);

  // z = enc @ v
  z_partial_mfma<<<512, 256, 0, stream>>>(mixed, v, Mf, zpart);
  z_merge<<<128, 256, 0, stream>>>(zpart, Sf, z);

  // o = dec^T @ z
  decode_o_mfma<<<512, 256, 0, stream>>>(mixed, z, o);

  // final: out = o @ out_w^T + out_b  (f32 into d_out, overwrites mixed)
  FArgs a3;
  a3.w[0] = wbf + 524288; a3.b[0] = outb;
  for (int i = 1; i < 5; ++i) { a3.w[i] = nullptr; a3.b[i] = nullptr; }
  fused_mlp<2><<<G, 256, 0, stream>>>(nullptr, o, a3, (float*)d_out, nullptr, nullptr, nullptr);
}